// Round 16
// baseline (5824.706 us; speedup 1.0000x reference)
//
#include <hip/hip_runtime.h>
#include <hip/hip_fp16.h>

#define BB 64
#define TT 2048
#define DD 256
#define HH 256
#define CHUNK 256
#define NCHUNK 8
#define PB 4          // batches per serial block
#define RS 264        // A-row stride (f16)
#define NSER 16       // serial blocks
#define GRID 240      // total persistent blocks

typedef _Float16 f16x8 __attribute__((ext_vector_type(8)));
typedef _Float16 f16x4 __attribute__((ext_vector_type(4)));
typedef _Float16 h2t   __attribute__((ext_vector_type(2)));
typedef float    f32x4 __attribute__((ext_vector_type(4)));
union V8 { f16x8 v; h2t p[4]; };

__device__ __forceinline__ float sigm(float v){ return __builtin_amdgcn_rcpf(1.f+__expf(-v)); }
__device__ __forceinline__ float tanh_f(float v){ float e=__expf(2.f*v); return 1.f-2.f*__builtin_amdgcn_rcpf(e+1.f); }

// Pack W [256][1024] f32 (k-major) into f16 layout [k/8][1024][8]
__global__ void pack_w(const float* __restrict__ w, _Float16* __restrict__ o) {
    int idx = blockIdx.x * 256 + threadIdx.x;
    int j = idx & 1023;
    int k = idx >> 10;
    o[(((k >> 3) * 1024) + j) * 8 + (k & 7)] = (_Float16)w[idx];
}

// ---- grid barrier: flat monotonic counter, device scope, fenced ----
__device__ __forceinline__ void gridbar(int* bar, int gen) {
    __syncthreads();
    if (threadIdx.x == 0) {
        __builtin_amdgcn_fence(__ATOMIC_RELEASE, "agent");
        __hip_atomic_fetch_add(bar, 1, __ATOMIC_RELAXED, __HIP_MEMORY_SCOPE_AGENT);
        while (__hip_atomic_load(bar, __ATOMIC_RELAXED, __HIP_MEMORY_SCOPE_AGENT) < GRID * gen)
            __builtin_amdgcn_s_sleep(8);
        __builtin_amdgcn_fence(__ATOMIC_ACQUIRE, "agent");
    }
    __syncthreads();
}

union SMem {
    struct { _Float16 A[2 * 16 * RS]; _Float16 Wl[8 * 1024 * 8]; } s;  // 147,968 B
    _Float16 xl[64 * 280];
};

// gx = x @ W_xh + (b_xh + b_hh) for chunk c, grid-strided over gemm blocks.
// Layout: [t 256][sblk 16][wave 8][b_local 4][dim 32][gate 4] f16.
__device__ void gemm_chunk(const float* __restrict__ x, const f16x8* __restrict__ wxp,
                           const float* __restrict__ b_xh, const float* __restrict__ b_hh,
                           _Float16* __restrict__ gxb, int c, _Float16* xl)
{
    const int tid = threadIdx.x;
    const int t0 = c << 8;
    const int tx = tid & 31;       // dim within block's 32-dim slice
    const int ty = tid >> 5;       // row group 0..15
    for (int T = (int)blockIdx.x - NSER; T < 2048; T += (GRID - NSER)) {
        const int rb = T >> 3, nb = T & 7;
        const int d = nb * 32 + tx;                 // this thread's dim
        for (int it = 0; it < 8; ++it) {
            int idx = it * 512 + tid, row = idx >> 6, kq = idx & 63;
            int rlin = rb * 64 + row, b = rlin >> 8, tl = rlin & 255;
            float4 v = *(const float4*)&x[((size_t)b * TT + t0 + tl) * DD + kq * 4];
            f16x4 h; h[0]=(_Float16)v.x; h[1]=(_Float16)v.y; h[2]=(_Float16)v.z; h[3]=(_Float16)v.w;
            *(f16x4*)&xl[row * 280 + kq * 4] = h;
        }
        __syncthreads();
        float acc[4][4] = {};                       // [row][gate]
#pragma unroll 2
        for (int kk = 0; kk < 32; ++kk) {
            V8 wv[4], xv[4];
#pragma unroll
            for (int g = 0; g < 4; ++g) wv[g].v = wxp[kk * 1024 + g * 256 + d];
#pragma unroll
            for (int r = 0; r < 4; ++r) xv[r].v = *(const f16x8*)&xl[(ty + 16 * r) * 280 + kk * 8];
#pragma unroll
            for (int r = 0; r < 4; ++r)
#pragma unroll
                for (int g = 0; g < 4; ++g)
#pragma unroll
                    for (int q = 0; q < 4; ++q)
                        acc[r][g] = __builtin_amdgcn_fdot2(xv[r].p[q], wv[g].p[q], acc[r][g], false);
        }
        __syncthreads();
        float bb[4];
#pragma unroll
        for (int g = 0; g < 4; ++g) bb[g] = b_xh[g * 256 + d] + b_hh[g * 256 + d];
#pragma unroll
        for (int r = 0; r < 4; ++r) {
            int rlin = rb * 64 + ty + 16 * r, b = rlin >> 8, tl = rlin & 255;
            f16x4 o;
#pragma unroll
            for (int g = 0; g < 4; ++g) o[g] = (_Float16)(acc[r][g] + bb[g]);
            *(f16x4*)&gxb[(((size_t)tl * 16 + (b >> 2)) * 8 + nb) * 512 + (b & 3) * 128 + tx * 4] = o;
        }
    }
}

// ================= serial macros =================
#define FOR_GDH(M) M(0,0) M(0,1) M(1,0) M(1,1) M(2,0) M(2,1) M(3,0) M(3,1)

#define DECLW(g,dh) f16x8 wf_##g##_##dh##_0, wf_##g##_##dh##_1, wf_##g##_##dh##_2, \
                          wf_##g##_##dh##_3, wf_##g##_##dh##_4, wf_##g##_##dh##_5;

#define LOADW1(g,dh,kt) { f16x8 t_; \
    _Pragma("unroll") \
    for (int e = 0; e < 8; ++e) \
        t_[e] = (_Float16)W_hh[(size_t)((kt)*32 + l4*8 + e)*1024 + (g)*256 + wbase + (dh)*16 + l15]; \
    wf_##g##_##dh##_##kt = t_; }

#define LOADW(g,dh) LOADW1(g,dh,0) LOADW1(g,dh,1) LOADW1(g,dh,2) \
                    LOADW1(g,dh,3) LOADW1(g,dh,4) LOADW1(g,dh,5)

// swizzled A fragment read: granule (kt*4+l4) + 2*(row>>3), row = l15
#define ARD(kt) (*(const f16x8*)&Ab[((((kt)*4 + l4 + aoff) & 31) << 3)])

#define KTR(kt,dh) { f16x8 af_ = ARD(kt); \
    ac0_ = __builtin_amdgcn_mfma_f32_16x16x32_f16(af_, wf_0_##dh##_##kt, ac0_, 0,0,0); \
    ac1_ = __builtin_amdgcn_mfma_f32_16x16x32_f16(af_, wf_1_##dh##_##kt, ac1_, 0,0,0); \
    ac2_ = __builtin_amdgcn_mfma_f32_16x16x32_f16(af_, wf_2_##dh##_##kt, ac2_, 0,0,0); \
    ac3_ = __builtin_amdgcn_mfma_f32_16x16x32_f16(af_, wf_3_##dh##_##kt, ac3_, 0,0,0); }

#define BLD(g,dh,kt) (*(const f16x8*)&Wl[(size_t)((((kt)-6)*4 + l4)*1024 + (g)*256 + wbase + (dh)*16 + l15)*8])

#define KTL(kt,dh) { f16x8 af_ = ARD(kt); \
    ac0_ = __builtin_amdgcn_mfma_f32_16x16x32_f16(af_, BLD(0,dh,kt), ac0_, 0,0,0); \
    ac1_ = __builtin_amdgcn_mfma_f32_16x16x32_f16(af_, BLD(1,dh,kt), ac1_, 0,0,0); \
    ac2_ = __builtin_amdgcn_mfma_f32_16x16x32_f16(af_, BLD(2,dh,kt), ac2_, 0,0,0); \
    ac3_ = __builtin_amdgcn_mfma_f32_16x16x32_f16(af_, BLD(3,dh,kt), ac3_, 0,0,0); }

// One batch per lane-group: batch = blk*4 + l4, rows 4*l4 (h0), 4*l4+1 (h1).
// A-writes granule-swizzled: granule' = (granule + 2*(row>>3)) & 31, row>>3 = l4>>1.
#define UPD(dh) { \
    const int gb_ = blk*PB + l4; \
    const int d_  = wbase + (dh)*16 + l15; \
    float h0n_ = 0.f, h1n_ = 0.f; \
    if (l0act) { \
        float gi_ = ac0_[0] + (float)gv_##dh[0]; \
        float gf_ = ac1_[0] + (float)gv_##dh[1]; \
        float gg_ = ac2_[0] + (float)gv_##dh[2]; \
        float go_ = ac3_[0] + (float)gv_##dh[3]; \
        c0s_##dh = c0s_##dh*sigm(gf_) + sigm(gi_)*tanh_f(gg_); \
        h0n_ = sigm(go_)*tanh_f(c0s_##dh); \
    } \
    if (l1act) { \
        float gi_ = ac0_[0] + ac0_[1] + bh2_##dh##_0; \
        float gf_ = ac1_[0] + ac1_[1] + bh2_##dh##_1; \
        float gg_ = ac2_[0] + ac2_[1] + bh2_##dh##_2; \
        float go_ = ac3_[0] + ac3_[1] + bh2_##dh##_3; \
        c1s_##dh = c1s_##dh*sigm(gf_) + sigm(gi_)*tanh_f(gg_); \
        h1n_ = sigm(go_)*tanh_f(c1s_##dh); \
        out[((size_t)gb_*TT + (t0 + p - 1))*HH + d_] = h1n_; \
    } \
    A[(parx*16 + 4*l4 + 0)*RS + ((((d_>>3) + woff) & 31) << 3) + (d_ & 7)] = (_Float16)h0n_; \
    A[(parx*16 + 4*l4 + 1)*RS + ((((d_>>3) + woff) & 31) << 3) + (d_ & 7)] = (_Float16)h1n_; \
    if (lastc) { \
        if (l0act && p == CHUNK-1) { out[FIN + gb_*256 + d_] = h0n_; out[FIN + 32768 + gb_*256 + d_] = c0s_##dh; } \
        if (p == nph-1) { out[FIN + 16384 + gb_*256 + d_] = h1n_; out[FIN + 49152 + gb_*256 + d_] = c1s_##dh; } \
    } }

#define HALF(dh) { \
    f16x4 gv_##dh = {}; \
    if (l0act) \
        gv_##dh = *(const f16x4*)&gxp[l4*128 + (dh)*64 + l15*4]; \
    f32x4 ac0_ = {}, ac1_ = {}, ac2_ = {}, ac3_ = {}; \
    KTR(0,dh) KTR(1,dh) KTR(2,dh) KTR(3,dh) KTR(4,dh) KTR(5,dh) \
    KTL(6,dh) KTL(7,dh) \
    UPD(dh) }

// Persistent fused kernel: blocks 0..15 = serial recurrence, rest = gx GEMM.
__global__ __launch_bounds__(512, 2) void lstm_coop(
    const float* __restrict__ x,
    const _Float16* __restrict__ wxp16,
    const float* __restrict__ b_xh, const float* __restrict__ b_hh,
    const float* __restrict__ W_hh,
    float* __restrict__ out,
    _Float16* __restrict__ gx0, _Float16* __restrict__ gx1,
    int* __restrict__ bar, int overlap)
{
    __shared__ SMem sm;
    const int tid = threadIdx.x;
    const f16x8* wxp = (const f16x8*)wxp16;

    if (blockIdx.x < NSER) {
        // ================= serial path =================
        _Float16* A  = sm.s.A;
        _Float16* Wl = sm.s.Wl;
        const int blk = blockIdx.x;
        const int l   = tid & 63;
        const int l15 = l & 15;
        const int l4  = l >> 4;
        const int w   = tid >> 6;
        const int wbase = w * 32;
        const int aoff = (l15 >> 3) << 1;   // read-side granule offset (row = l15)
        const int woff = (l4 >> 1) << 1;    // write-side granule offset (row = 4*l4+{0,1})

        // LDS weights: k in [192,256)
        for (int v = tid; v < 8192; v += 512) {
            int cr = v >> 10, col = v & 1023;
            f16x8 t;
#pragma unroll
            for (int e = 0; e < 8; ++e)
                t[e] = (_Float16)W_hh[(size_t)(192 + cr * 8 + e) * 1024 + col];
            *(f16x8*)&Wl[(size_t)v * 8] = t;
        }
        // register weights: k in [0,192), 48 named f16x8
        FOR_GDH(DECLW)
        FOR_GDH(LOADW)

        float bh2_0_0 = 2.f*b_hh[0*256 + wbase + l15],      bh2_0_1 = 2.f*b_hh[1*256 + wbase + l15];
        float bh2_0_2 = 2.f*b_hh[2*256 + wbase + l15],      bh2_0_3 = 2.f*b_hh[3*256 + wbase + l15];
        float bh2_1_0 = 2.f*b_hh[0*256 + wbase + 16 + l15], bh2_1_1 = 2.f*b_hh[1*256 + wbase + 16 + l15];
        float bh2_1_2 = 2.f*b_hh[2*256 + wbase + 16 + l15], bh2_1_3 = 2.f*b_hh[3*256 + wbase + 16 + l15];

        float c0s_0 = 0.f, c0s_1 = 0.f, c1s_0 = 0.f, c1s_1 = 0.f;
        for (int i = tid; i < 16 * RS; i += 512) A[i] = (_Float16)0;   // parity-0 A = 0

        int gen = 0;
        gridbar(bar, ++gen);                 // wait for chunk-0 gx

        const size_t FIN = (size_t)BB * TT * HH;
        for (int c = 0; c < NCHUNK; ++c) {
            const _Float16* gxc = (c & 1) ? gx1 : gx0;
            const int t0 = c << 8;
            const int nph = (c == NCHUNK - 1) ? CHUNK + 1 : CHUNK;
            const bool lastc = (c == NCHUNK - 1);
            // phase-incremented gx base: [t][blk][w] slice start
            const _Float16* gxp = gxc + (size_t)blk * 4096 + (size_t)w * 512;
            for (int p = 0; p < nph; ++p) {
                const int par = p & 1, parx = par ^ 1;
                const bool l0act = (p < CHUNK);
                const bool l1act = (c > 0) || (p > 0);
                const _Float16* Ab = A + (par * 16 + l15) * RS;
                HALF(0)
                HALF(1)
                gxp += 65536;
                if (p + 1 < nph) {
                    // raw barrier: only LDS (A) writes must be visible cross-wave.
                    asm volatile("s_waitcnt lgkmcnt(0)" ::: "memory");
                    __builtin_amdgcn_s_barrier();
                }
            }
            if (c < NCHUNK - 1) {
                gridbar(bar, ++gen);
                if (!overlap) gridbar(bar, ++gen);
            }
        }
    } else {
        // ================= gemm path =================
        gemm_chunk(x, wxp, b_xh, b_hh, gx0, 0, sm.xl);
        int gen = 0;
        gridbar(bar, ++gen);
        for (int c = 0; c < NCHUNK - 1; ++c) {
            if (overlap) {
                gemm_chunk(x, wxp, b_xh, b_hh, ((c + 1) & 1) ? gx1 : gx0, c + 1, sm.xl);
                gridbar(bar, ++gen);
            } else {
                gridbar(bar, ++gen);
                gemm_chunk(x, wxp, b_xh, b_hh, gx0, c + 1, sm.xl);
                gridbar(bar, ++gen);
            }
        }
    }
}

extern "C" void kernel_launch(void* const* d_in, const int* in_sizes, int n_in,
                              void* d_out, int out_size, void* d_ws, size_t ws_size,
                              hipStream_t stream) {
    const float* x    = (const float*)d_in[0];
    const float* W_xh = (const float*)d_in[1];
    const float* b_xh = (const float*)d_in[2];
    const float* W_hh = (const float*)d_in[3];
    const float* b_hh = (const float*)d_in[4];
    float* out = (float*)d_out;

    char* ws = (char*)d_ws;
    _Float16* wxp = (_Float16*)ws;                          // 512 KB packed W_xh
    int* bar      = (int*)(ws + (512 << 10));               // barrier counter
    char* gxbase  = ws + (512 << 10) + 256;
    const size_t gxb = (size_t)64 * 256 * 1024 * 2;         // 33.55 MB per gx buffer
    _Float16* gx0 = (_Float16*)gxbase;
    int overlap = (ws_size >= (size_t)(512 << 10) + 256 + 2 * gxb) ? 1 : 0;
    _Float16* gx1 = overlap ? (_Float16*)(gxbase + gxb) : gx0;

    pack_w<<<1024, 256, 0, stream>>>(W_xh, wxp);
    hipMemsetAsync(bar, 0, 4, stream);
    lstm_coop<<<GRID, 512, 0, stream>>>(x, wxp, b_xh, b_hh, W_hh, out, gx0, gx1, bar, overlap);
}

// Round 17
// 3094.646 us; speedup vs baseline: 1.8822x; 1.8822x over previous
//
#include <hip/hip_runtime.h>
#include <hip/hip_fp16.h>

#define BB 64
#define TT 2048
#define DD 256
#define HH 256
#define CHUNK 256
#define NCHUNK 8
#define PB 4          // batches per serial block
#define ARS 272       // A row stride (bytes, i8) — 2-way bank alias only
#define NSER 16       // serial blocks
#define GRID 240      // total persistent blocks

typedef _Float16 f16x8 __attribute__((ext_vector_type(8)));
typedef _Float16 f16x4 __attribute__((ext_vector_type(4)));
typedef _Float16 h2t   __attribute__((ext_vector_type(2)));
typedef float    f32x4 __attribute__((ext_vector_type(4)));
typedef int      i32x4 __attribute__((ext_vector_type(4)));
union V8 { f16x8 v; h2t p[4]; };

__device__ __forceinline__ float sigm(float v){ return __builtin_amdgcn_rcpf(1.f+__expf(-v)); }
__device__ __forceinline__ float tanh_f(float v){ float e=__expf(2.f*v); return 1.f-2.f*__builtin_amdgcn_rcpf(e+1.f); }

// Pack W [256][1024] f32 (k-major) into f16 layout [k/8][1024][8]
__global__ void pack_w(const float* __restrict__ w, _Float16* __restrict__ o) {
    int idx = blockIdx.x * 256 + threadIdx.x;
    int j = idx & 1023;
    int k = idx >> 10;
    o[(((k >> 3) * 1024) + j) * 8 + (k & 7)] = (_Float16)w[idx];
}

// ---- grid barrier: flat monotonic counter, device scope, fenced ----
__device__ __forceinline__ void gridbar(int* bar, int gen) {
    __syncthreads();
    if (threadIdx.x == 0) {
        __builtin_amdgcn_fence(__ATOMIC_RELEASE, "agent");
        __hip_atomic_fetch_add(bar, 1, __ATOMIC_RELAXED, __HIP_MEMORY_SCOPE_AGENT);
        while (__hip_atomic_load(bar, __ATOMIC_RELAXED, __HIP_MEMORY_SCOPE_AGENT) < GRID * gen)
            __builtin_amdgcn_s_sleep(8);
        __builtin_amdgcn_fence(__ATOMIC_ACQUIRE, "agent");
    }
    __syncthreads();
}

union SMem {
    struct { char A[2 * 16 * ARS]; float cmax[1024]; } s;   // 8704 + 4096 B
    _Float16 xl[64 * 280];                                  // 35840 B
};

// gx = x @ W_xh + (b_xh + b_hh) for chunk c, grid-strided over gemm blocks.
// Layout: [t 256][sblk 16][wave 8][b_local 4][dim 32][gate 4] f16.
__device__ void gemm_chunk(const float* __restrict__ x, const f16x8* __restrict__ wxp,
                           const float* __restrict__ b_xh, const float* __restrict__ b_hh,
                           _Float16* __restrict__ gxb, int c, _Float16* xl)
{
    const int tid = threadIdx.x;
    const int t0 = c << 8;
    const int tx = tid & 31;
    const int ty = tid >> 5;
    for (int T = (int)blockIdx.x - NSER; T < 2048; T += (GRID - NSER)) {
        const int rb = T >> 3, nb = T & 7;
        const int d = nb * 32 + tx;
        for (int it = 0; it < 8; ++it) {
            int idx = it * 512 + tid, row = idx >> 6, kq = idx & 63;
            int rlin = rb * 64 + row, b = rlin >> 8, tl = rlin & 255;
            float4 v = *(const float4*)&x[((size_t)b * TT + t0 + tl) * DD + kq * 4];
            f16x4 h; h[0]=(_Float16)v.x; h[1]=(_Float16)v.y; h[2]=(_Float16)v.z; h[3]=(_Float16)v.w;
            *(f16x4*)&xl[row * 280 + kq * 4] = h;
        }
        __syncthreads();
        float acc[4][4] = {};
#pragma unroll 2
        for (int kk = 0; kk < 32; ++kk) {
            V8 wv[4], xv[4];
#pragma unroll
            for (int g = 0; g < 4; ++g) wv[g].v = wxp[kk * 1024 + g * 256 + d];
#pragma unroll
            for (int r = 0; r < 4; ++r) xv[r].v = *(const f16x8*)&xl[(ty + 16 * r) * 280 + kk * 8];
#pragma unroll
            for (int r = 0; r < 4; ++r)
#pragma unroll
                for (int g = 0; g < 4; ++g)
#pragma unroll
                    for (int q = 0; q < 4; ++q)
                        acc[r][g] = __builtin_amdgcn_fdot2(xv[r].p[q], wv[g].p[q], acc[r][g], false);
        }
        __syncthreads();
        float bb[4];
#pragma unroll
        for (int g = 0; g < 4; ++g) bb[g] = b_xh[g * 256 + d] + b_hh[g * 256 + d];
#pragma unroll
        for (int r = 0; r < 4; ++r) {
            int rlin = rb * 64 + ty + 16 * r, b = rlin >> 8, tl = rlin & 255;
            f16x4 o;
#pragma unroll
            for (int g = 0; g < 4; ++g) o[g] = (_Float16)(acc[r][g] + bb[g]);
            *(f16x4*)&gxb[(((size_t)tl * 16 + (b >> 2)) * 8 + nb) * 512 + (b & 3) * 128 + tx * 4] = o;
        }
    }
}

// ================= serial macros (i8 core) =================
#define FOR_GD(M) M(0,0) M(0,1) M(1,0) M(1,1) M(2,0) M(2,1) M(3,0) M(3,1)

#define DECLQ(g,dh) i32x4 wq_##g##_##dh##_0, wq_##g##_##dh##_1, wq_##g##_##dh##_2, wq_##g##_##dh##_3; \
                    float sc_##g##_##dh;

#define LOADQ1(g,dh,kt,rs_) { \
    union { char c[16]; i32x4 v; } u_; \
    _Pragma("unroll") \
    for (int e = 0; e < 16; ++e) { \
        float w_ = W_hh[(size_t)((kt)*64 + l4*16 + e)*1024 + (g)*256 + wbase + (dh)*16 + l15]; \
        u_.c[e] = (char)(int)rintf(w_ * rs_); \
    } \
    wq_##g##_##dh##_##kt = u_.v; }

#define LOADQ(g,dh) { \
    float cm_ = cmax[(g)*256 + wbase + (dh)*16 + l15]; \
    float rs_ = 127.f / cm_; \
    sc_##g##_##dh = cm_ * 6.2000124e-5f;   /* cm/(127*127) */ \
    LOADQ1(g,dh,0,rs_) LOADQ1(g,dh,1,rs_) LOADQ1(g,dh,2,rs_) LOADQ1(g,dh,3,rs_) }

// per kt: one b128 A-frag read shared by all 8 (gate,dh) MFMAs
#define QKT(kt) { \
    i32x4 af_ = *(const i32x4*)&Apar[(kt)*64 + l4*16]; \
    ia0_0 = __builtin_amdgcn_mfma_i32_16x16x64_i8(af_, wq_0_0_##kt, ia0_0, 0,0,0); \
    ia1_0 = __builtin_amdgcn_mfma_i32_16x16x64_i8(af_, wq_1_0_##kt, ia1_0, 0,0,0); \
    ia2_0 = __builtin_amdgcn_mfma_i32_16x16x64_i8(af_, wq_2_0_##kt, ia2_0, 0,0,0); \
    ia3_0 = __builtin_amdgcn_mfma_i32_16x16x64_i8(af_, wq_3_0_##kt, ia3_0, 0,0,0); \
    ia0_1 = __builtin_amdgcn_mfma_i32_16x16x64_i8(af_, wq_0_1_##kt, ia0_1, 0,0,0); \
    ia1_1 = __builtin_amdgcn_mfma_i32_16x16x64_i8(af_, wq_1_1_##kt, ia1_1, 0,0,0); \
    ia2_1 = __builtin_amdgcn_mfma_i32_16x16x64_i8(af_, wq_2_1_##kt, ia2_1, 0,0,0); \
    ia3_1 = __builtin_amdgcn_mfma_i32_16x16x64_i8(af_, wq_3_1_##kt, ia3_1, 0,0,0); }

// One batch per lane-group: batch = blk*4 + l4; acc reg 0 = h0 row, reg 1 = h1 row.
#define UPD(dh) { \
    const int gb_ = blk*PB + l4; \
    const int d_  = wbase + (dh)*16 + l15; \
    float h0n_ = 0.f, h1n_ = 0.f; \
    if (l0act) { \
        float gi_ = (float)ia0_##dh[0] * sc_0_##dh + (float)gv_##dh[0]; \
        float gf_ = (float)ia1_##dh[0] * sc_1_##dh + (float)gv_##dh[1]; \
        float gg_ = (float)ia2_##dh[0] * sc_2_##dh + (float)gv_##dh[2]; \
        float go_ = (float)ia3_##dh[0] * sc_3_##dh + (float)gv_##dh[3]; \
        c0s_##dh = c0s_##dh*sigm(gf_) + sigm(gi_)*tanh_f(gg_); \
        h0n_ = sigm(go_)*tanh_f(c0s_##dh); \
    } \
    if (l1act) { \
        float gi_ = (float)(ia0_##dh[0]+ia0_##dh[1]) * sc_0_##dh + bh2_##dh##_0; \
        float gf_ = (float)(ia1_##dh[0]+ia1_##dh[1]) * sc_1_##dh + bh2_##dh##_1; \
        float gg_ = (float)(ia2_##dh[0]+ia2_##dh[1]) * sc_2_##dh + bh2_##dh##_2; \
        float go_ = (float)(ia3_##dh[0]+ia3_##dh[1]) * sc_3_##dh + bh2_##dh##_3; \
        c1s_##dh = c1s_##dh*sigm(gf_) + sigm(gi_)*tanh_f(gg_); \
        h1n_ = sigm(go_)*tanh_f(c1s_##dh); \
        out[((size_t)gb_*TT + (t0 + p - 1))*HH + d_] = h1n_; \
    } \
    A[(parx*16 + 4*l4 + 0)*ARS + d_] = (char)(int)rintf(h0n_ * 127.f); \
    A[(parx*16 + 4*l4 + 1)*ARS + d_] = (char)(int)rintf(h1n_ * 127.f); \
    if (lastc) { \
        if (l0act && p == CHUNK-1) { out[FIN + gb_*256 + d_] = h0n_; out[FIN + 32768 + gb_*256 + d_] = c0s_##dh; } \
        if (p == nph-1) { out[FIN + 16384 + gb_*256 + d_] = h1n_; out[FIN + 49152 + gb_*256 + d_] = c1s_##dh; } \
    } }

// Persistent fused kernel: blocks 0..15 = serial recurrence, rest = gx GEMM.
__global__ __launch_bounds__(512, 2) void lstm_coop(
    const float* __restrict__ x,
    const _Float16* __restrict__ wxp16,
    const float* __restrict__ b_xh, const float* __restrict__ b_hh,
    const float* __restrict__ W_hh,
    float* __restrict__ out,
    _Float16* __restrict__ gx0, _Float16* __restrict__ gx1,
    int* __restrict__ bar, int overlap)
{
    __shared__ SMem sm;
    const int tid = threadIdx.x;
    const f16x8* wxp = (const f16x8*)wxp16;

    if (blockIdx.x < NSER) {
        // ================= serial path (i8 MFMA core) =================
        char*  A    = sm.s.A;
        float* cmax = sm.s.cmax;
        const int blk = blockIdx.x;
        const int l   = tid & 63;
        const int l15 = l & 15;
        const int l4  = l >> 4;
        const int w   = tid >> 6;
        const int wbase = w * 32;

        // per-column absmax of W_hh (cooperative)
        for (int col = tid; col < 1024; col += 512) {
            float m = 1e-20f;
            for (int k = 0; k < 256; ++k)
                m = fmaxf(m, fabsf(W_hh[(size_t)k * 1024 + col]));
            cmax[col] = m;
        }
        __syncthreads();

        // quantized weight registers: 32 named i32x4 (=128 regs) + 8 scales
        FOR_GD(DECLQ)
        FOR_GD(LOADQ)

        float bh2_0_0 = 2.f*b_hh[0*256 + wbase + l15],      bh2_0_1 = 2.f*b_hh[1*256 + wbase + l15];
        float bh2_0_2 = 2.f*b_hh[2*256 + wbase + l15],      bh2_0_3 = 2.f*b_hh[3*256 + wbase + l15];
        float bh2_1_0 = 2.f*b_hh[0*256 + wbase + 16 + l15], bh2_1_1 = 2.f*b_hh[1*256 + wbase + 16 + l15];
        float bh2_1_2 = 2.f*b_hh[2*256 + wbase + 16 + l15], bh2_1_3 = 2.f*b_hh[3*256 + wbase + 16 + l15];

        float c0s_0 = 0.f, c0s_1 = 0.f, c1s_0 = 0.f, c1s_1 = 0.f;
        for (int i = tid; i < 2 * 16 * ARS; i += 512) A[i] = 0;   // h(0) = 0

        int gen = 0;
        gridbar(bar, ++gen);                 // wait for chunk-0 gx

        const size_t FIN = (size_t)BB * TT * HH;
        for (int c = 0; c < NCHUNK; ++c) {
            const _Float16* gxc = (c & 1) ? gx1 : gx0;
            const int t0 = c << 8;
            const int nph = (c == NCHUNK - 1) ? CHUNK + 1 : CHUNK;
            const bool lastc = (c == NCHUNK - 1);
            const _Float16* gxp = gxc + (size_t)blk * 4096 + (size_t)w * 512;
            for (int p = 0; p < nph; ++p) {
                const int par = p & 1, parx = par ^ 1;
                const bool l0act = (p < CHUNK);
                const bool l1act = (c > 0) || (p > 0);
                const char* Apar = A + par * (16 * ARS) + l15 * ARS;

                f16x4 gv_0 = {}, gv_1 = {};
                if (l0act) {
                    gv_0 = *(const f16x4*)&gxp[l4*128 + l15*4];
                    gv_1 = *(const f16x4*)&gxp[l4*128 + 64 + l15*4];
                }

                i32x4 ia0_0 = {}, ia1_0 = {}, ia2_0 = {}, ia3_0 = {};
                i32x4 ia0_1 = {}, ia1_1 = {}, ia2_1 = {}, ia3_1 = {};
                QKT(0) QKT(1) QKT(2) QKT(3)

                UPD(0)
                UPD(1)

                gxp += 65536;
                if (p + 1 < nph) {
                    // only LDS (A) writes need cross-wave visibility
                    asm volatile("s_waitcnt lgkmcnt(0)" ::: "memory");
                    __builtin_amdgcn_s_barrier();
                }
            }
            if (c < NCHUNK - 1) {
                gridbar(bar, ++gen);
                if (!overlap) gridbar(bar, ++gen);
            }
        }
    } else {
        // ================= gemm path =================
        gemm_chunk(x, wxp, b_xh, b_hh, gx0, 0, sm.xl);
        int gen = 0;
        gridbar(bar, ++gen);
        for (int c = 0; c < NCHUNK - 1; ++c) {
            if (overlap) {
                gemm_chunk(x, wxp, b_xh, b_hh, ((c + 1) & 1) ? gx1 : gx0, c + 1, sm.xl);
                gridbar(bar, ++gen);
            } else {
                gridbar(bar, ++gen);
                gemm_chunk(x, wxp, b_xh, b_hh, gx0, c + 1, sm.xl);
                gridbar(bar, ++gen);
            }
        }
    }
}

extern "C" void kernel_launch(void* const* d_in, const int* in_sizes, int n_in,
                              void* d_out, int out_size, void* d_ws, size_t ws_size,
                              hipStream_t stream) {
    const float* x    = (const float*)d_in[0];
    const float* W_xh = (const float*)d_in[1];
    const float* b_xh = (const float*)d_in[2];
    const float* W_hh = (const float*)d_in[3];
    const float* b_hh = (const float*)d_in[4];
    float* out = (float*)d_out;

    char* ws = (char*)d_ws;
    _Float16* wxp = (_Float16*)ws;                          // 512 KB packed W_xh
    int* bar      = (int*)(ws + (512 << 10));               // barrier counter
    char* gxbase  = ws + (512 << 10) + 256;
    const size_t gxb = (size_t)64 * 256 * 1024 * 2;         // 33.55 MB per gx buffer
    _Float16* gx0 = (_Float16*)gxbase;
    int overlap = (ws_size >= (size_t)(512 << 10) + 256 + 2 * gxb) ? 1 : 0;
    _Float16* gx1 = overlap ? (_Float16*)(gxbase + gxb) : gx0;

    pack_w<<<1024, 256, 0, stream>>>(W_xh, wxp);
    hipMemsetAsync(bar, 0, 4, stream);
    lstm_coop<<<GRID, 512, 0, stream>>>(x, wxp, b_xh, b_hh, W_hh, out, gx0, gx1, bar, overlap);
}

// Round 18
// 2749.673 us; speedup vs baseline: 2.1183x; 1.1255x over previous
//
#include <hip/hip_runtime.h>
#include <hip/hip_fp16.h>

#define BB 64
#define TT 2048
#define DD 256
#define HH 256
#define CHUNK 256
#define NCHUNK 8
#define PB 4          // batches per serial block
#define ARS 272       // A row stride (bytes, i8)
#define NSER 16       // serial blocks
#define GRID 240      // total persistent blocks
#define NTHR 1024

typedef _Float16 f16x8 __attribute__((ext_vector_type(8)));
typedef _Float16 f16x4 __attribute__((ext_vector_type(4)));
typedef _Float16 h2t   __attribute__((ext_vector_type(2)));
typedef float    f32x4 __attribute__((ext_vector_type(4)));
typedef int      i32x4 __attribute__((ext_vector_type(4)));
union V8 { f16x8 v; h2t p[4]; };

__device__ __forceinline__ float sigm(float v){ return __builtin_amdgcn_rcpf(1.f+__expf(-v)); }
__device__ __forceinline__ float tanh_f(float v){ float e=__expf(2.f*v); return 1.f-2.f*__builtin_amdgcn_rcpf(e+1.f); }

// Pack W [256][1024] f32 (k-major) into f16 layout [k/8][1024][8]
__global__ void pack_w(const float* __restrict__ w, _Float16* __restrict__ o) {
    int idx = blockIdx.x * 256 + threadIdx.x;
    int j = idx & 1023;
    int k = idx >> 10;
    o[(((k >> 3) * 1024) + j) * 8 + (k & 7)] = (_Float16)w[idx];
}

// ---- grid barrier: flat monotonic counter, device scope, fenced ----
__device__ __forceinline__ void gridbar(int* bar, int gen) {
    __syncthreads();
    if (threadIdx.x == 0) {
        __builtin_amdgcn_fence(__ATOMIC_RELEASE, "agent");
        __hip_atomic_fetch_add(bar, 1, __ATOMIC_RELAXED, __HIP_MEMORY_SCOPE_AGENT);
        while (__hip_atomic_load(bar, __ATOMIC_RELAXED, __HIP_MEMORY_SCOPE_AGENT) < GRID * gen)
            __builtin_amdgcn_s_sleep(8);
        __builtin_amdgcn_fence(__ATOMIC_ACQUIRE, "agent");
    }
    __syncthreads();
}

union SMem {
    struct { char A[2 * 16 * ARS]; float cmax[1024]; } s;   // 8704 + 4096 B
    _Float16 xl[64 * 280];                                  // 35840 B
};

// gx = x @ W_xh + (b_xh + b_hh) for chunk c, grid-strided. 1024 threads.
// Layout: [t 256][sblk 16][wave8 8][b_local 4][dim 32][gate 4] f16 (unchanged).
__device__ void gemm_chunk(const float* __restrict__ x, const f16x8* __restrict__ wxp,
                           const float* __restrict__ b_xh, const float* __restrict__ b_hh,
                           _Float16* __restrict__ gxb, int c, _Float16* xl)
{
    const int tid = threadIdx.x;
    const int t0 = c << 8;
    const int tx = tid & 31;
    const int ty = tid >> 5;       // 0..31
    for (int T = (int)blockIdx.x - NSER; T < 2048; T += (GRID - NSER)) {
        const int rb = T >> 3, nb = T & 7;
        const int d = nb * 32 + tx;
        for (int it = 0; it < 4; ++it) {
            int idx = it * 1024 + tid, row = idx >> 6, kq = idx & 63;
            int rlin = rb * 64 + row, b = rlin >> 8, tl = rlin & 255;
            float4 v = *(const float4*)&x[((size_t)b * TT + t0 + tl) * DD + kq * 4];
            f16x4 h; h[0]=(_Float16)v.x; h[1]=(_Float16)v.y; h[2]=(_Float16)v.z; h[3]=(_Float16)v.w;
            *(f16x4*)&xl[row * 280 + kq * 4] = h;
        }
        __syncthreads();
        float acc[2][4] = {};
#pragma unroll 2
        for (int kk = 0; kk < 32; ++kk) {
            V8 wv[4], xv[2];
#pragma unroll
            for (int g = 0; g < 4; ++g) wv[g].v = wxp[kk * 1024 + g * 256 + d];
#pragma unroll
            for (int r = 0; r < 2; ++r) xv[r].v = *(const f16x8*)&xl[(ty + 32 * r) * 280 + kk * 8];
#pragma unroll
            for (int r = 0; r < 2; ++r)
#pragma unroll
                for (int g = 0; g < 4; ++g)
#pragma unroll
                    for (int q = 0; q < 4; ++q)
                        acc[r][g] = __builtin_amdgcn_fdot2(xv[r].p[q], wv[g].p[q], acc[r][g], false);
        }
        __syncthreads();
        float bb[4];
#pragma unroll
        for (int g = 0; g < 4; ++g) bb[g] = b_xh[g * 256 + d] + b_hh[g * 256 + d];
#pragma unroll
        for (int r = 0; r < 2; ++r) {
            int rlin = rb * 64 + ty + 32 * r, b = rlin >> 8, tl = rlin & 255;
            f16x4 o;
#pragma unroll
            for (int g = 0; g < 4; ++g) o[g] = (_Float16)(acc[r][g] + bb[g]);
            *(f16x4*)&gxb[(((size_t)tl * 16 + (b >> 2)) * 8 + nb) * 512 + (b & 3) * 128 + tx * 4] = o;
        }
    }
}

// ================= serial macros (i8 core, 16-dim waves) =================
#define FOR_G(M) M(0) M(1) M(2) M(3)

#define DECLQ(g) i32x4 wq_##g##_0, wq_##g##_1, wq_##g##_2, wq_##g##_3; float sc_##g;

#define LOADQ1(g,kt,rs_) { \
    union { char c[16]; i32x4 v; } u_; \
    _Pragma("unroll") \
    for (int e = 0; e < 16; ++e) { \
        float w_ = W_hh[(size_t)((kt)*64 + l4*16 + e)*1024 + (g)*256 + wbase + l15]; \
        u_.c[e] = (char)(int)rintf(w_ * rs_); \
    } \
    wq_##g##_##kt = u_.v; }

#define LOADQ(g) { \
    float cm_ = cmax[(g)*256 + wbase + l15]; \
    float rs_ = 127.f / cm_; \
    sc_##g = cm_ * 6.2000124e-5f;   /* cm/(127*127) */ \
    LOADQ1(g,0,rs_) LOADQ1(g,1,rs_) LOADQ1(g,2,rs_) LOADQ1(g,3,rs_) }

// per kt: one b128 A-frag read shared by the 4 gate MFMAs
#define QKT(kt) { \
    i32x4 af_ = *(const i32x4*)&Apar[(kt)*64 + l4*16]; \
    ia0_ = __builtin_amdgcn_mfma_i32_16x16x64_i8(af_, wq_0_##kt, ia0_, 0,0,0); \
    ia1_ = __builtin_amdgcn_mfma_i32_16x16x64_i8(af_, wq_1_##kt, ia1_, 0,0,0); \
    ia2_ = __builtin_amdgcn_mfma_i32_16x16x64_i8(af_, wq_2_##kt, ia2_, 0,0,0); \
    ia3_ = __builtin_amdgcn_mfma_i32_16x16x64_i8(af_, wq_3_##kt, ia3_, 0,0,0); }

// One batch per lane-group: batch = blk*4 + l4; acc reg 0 = h0 row, reg 1 = h1 row.
#define UPD() { \
    const int gb_ = blk*PB + l4; \
    const int d_  = wbase + l15; \
    float h0n_ = 0.f, h1n_ = 0.f; \
    if (l0act) { \
        float gi_ = (float)ia0_[0] * sc_0 + (float)gv_[0]; \
        float gf_ = (float)ia1_[0] * sc_1 + (float)gv_[1]; \
        float gg_ = (float)ia2_[0] * sc_2 + (float)gv_[2]; \
        float go_ = (float)ia3_[0] * sc_3 + (float)gv_[3]; \
        c0s = c0s*sigm(gf_) + sigm(gi_)*tanh_f(gg_); \
        h0n_ = sigm(go_)*tanh_f(c0s); \
    } \
    if (l1act) { \
        float gi_ = (float)(ia0_[0]+ia0_[1]) * sc_0 + bh2_0; \
        float gf_ = (float)(ia1_[0]+ia1_[1]) * sc_1 + bh2_1; \
        float gg_ = (float)(ia2_[0]+ia2_[1]) * sc_2 + bh2_2; \
        float go_ = (float)(ia3_[0]+ia3_[1]) * sc_3 + bh2_3; \
        c1s = c1s*sigm(gf_) + sigm(gi_)*tanh_f(gg_); \
        h1n_ = sigm(go_)*tanh_f(c1s); \
        out[((size_t)gb_*TT + (t0 + p - 1))*HH + d_] = h1n_; \
    } \
    A[(parx*16 + 4*l4 + 0)*ARS + d_] = (char)(int)rintf(h0n_ * 127.f); \
    A[(parx*16 + 4*l4 + 1)*ARS + d_] = (char)(int)rintf(h1n_ * 127.f); \
    if (lastc) { \
        if (l0act && p == CHUNK-1) { out[FIN + gb_*256 + d_] = h0n_; out[FIN + 32768 + gb_*256 + d_] = c0s; } \
        if (p == nph-1) { out[FIN + 16384 + gb_*256 + d_] = h1n_; out[FIN + 49152 + gb_*256 + d_] = c1s; } \
    } }

// Persistent fused kernel: blocks 0..15 = serial recurrence (1024 thr, 16 waves,
// 4 waves/SIMD), rest = gx GEMM.
__global__ __launch_bounds__(NTHR, 1) void lstm_coop(
    const float* __restrict__ x,
    const _Float16* __restrict__ wxp16,
    const float* __restrict__ b_xh, const float* __restrict__ b_hh,
    const float* __restrict__ W_hh,
    float* __restrict__ out,
    _Float16* __restrict__ gx0, _Float16* __restrict__ gx1,
    int* __restrict__ bar, int overlap)
{
    __shared__ SMem sm;
    const int tid = threadIdx.x;
    const f16x8* wxp = (const f16x8*)wxp16;

    if (blockIdx.x < NSER) {
        // ================= serial path (i8 MFMA core, 16 waves) =================
        char*  A    = sm.s.A;
        float* cmax = sm.s.cmax;
        const int blk = blockIdx.x;
        const int l   = tid & 63;
        const int l15 = l & 15;
        const int l4  = l >> 4;
        const int w   = tid >> 6;          // 0..15
        const int wbase = w * 16;          // this wave's 16 dims

        // per-column absmax of W_hh (cooperative)
        for (int col = tid; col < 1024; col += NTHR) {
            float m = 1e-20f;
            for (int k = 0; k < 256; ++k)
                m = fmaxf(m, fabsf(W_hh[(size_t)k * 1024 + col]));
            cmax[col] = m;
        }
        __syncthreads();

        // quantized weight registers: 16 named i32x4 (=64 regs) + 4 scales
        FOR_G(DECLQ)
        FOR_G(LOADQ)

        float bh2_0 = 2.f*b_hh[0*256 + wbase + l15], bh2_1 = 2.f*b_hh[1*256 + wbase + l15];
        float bh2_2 = 2.f*b_hh[2*256 + wbase + l15], bh2_3 = 2.f*b_hh[3*256 + wbase + l15];

        float c0s = 0.f, c1s = 0.f;
        for (int i = tid; i < 2 * 16 * ARS; i += NTHR) A[i] = 0;   // h(0) = 0

        int gen = 0;
        gridbar(bar, ++gen);                 // wait for chunk-0 gx

        // gx sub-slice for this wave: wave8 = w>>1, dim-half = w&1
        const int goff = (w >> 1) * 512 + l4 * 128 + (w & 1) * 64 + l15 * 4;

        const size_t FIN = (size_t)BB * TT * HH;
        for (int c = 0; c < NCHUNK; ++c) {
            const _Float16* gxc = (c & 1) ? gx1 : gx0;
            const int t0 = c << 8;
            const int nph = (c == NCHUNK - 1) ? CHUNK + 1 : CHUNK;
            const bool lastc = (c == NCHUNK - 1);
            const _Float16* gxp = gxc + (size_t)blk * 4096 + goff;
            for (int p = 0; p < nph; ++p) {
                const int par = p & 1, parx = par ^ 1;
                const bool l0act = (p < CHUNK);
                const bool l1act = (c > 0) || (p > 0);
                const char* Apar = A + par * (16 * ARS) + l15 * ARS;

                f16x4 gv_ = {};
                if (l0act) gv_ = *(const f16x4*)gxp;

                i32x4 ia0_ = {}, ia1_ = {}, ia2_ = {}, ia3_ = {};
                QKT(0) QKT(1) QKT(2) QKT(3)

                UPD()

                gxp += 65536;
                if (p + 1 < nph) {
                    // only LDS (A) writes need cross-wave visibility
                    asm volatile("s_waitcnt lgkmcnt(0)" ::: "memory");
                    __builtin_amdgcn_s_barrier();
                }
            }
            if (c < NCHUNK - 1) {
                gridbar(bar, ++gen);
                if (!overlap) gridbar(bar, ++gen);
            }
        }
    } else {
        // ================= gemm path =================
        gemm_chunk(x, wxp, b_xh, b_hh, gx0, 0, sm.xl);
        int gen = 0;
        gridbar(bar, ++gen);
        for (int c = 0; c < NCHUNK - 1; ++c) {
            if (overlap) {
                gemm_chunk(x, wxp, b_xh, b_hh, ((c + 1) & 1) ? gx1 : gx0, c + 1, sm.xl);
                gridbar(bar, ++gen);
            } else {
                gridbar(bar, ++gen);
                gemm_chunk(x, wxp, b_xh, b_hh, gx0, c + 1, sm.xl);
                gridbar(bar, ++gen);
            }
        }
    }
}

extern "C" void kernel_launch(void* const* d_in, const int* in_sizes, int n_in,
                              void* d_out, int out_size, void* d_ws, size_t ws_size,
                              hipStream_t stream) {
    const float* x    = (const float*)d_in[0];
    const float* W_xh = (const float*)d_in[1];
    const float* b_xh = (const float*)d_in[2];
    const float* W_hh = (const float*)d_in[3];
    const float* b_hh = (const float*)d_in[4];
    float* out = (float*)d_out;

    char* ws = (char*)d_ws;
    _Float16* wxp = (_Float16*)ws;                          // 512 KB packed W_xh
    int* bar      = (int*)(ws + (512 << 10));               // barrier counter
    char* gxbase  = ws + (512 << 10) + 256;
    const size_t gxb = (size_t)64 * 256 * 1024 * 2;         // 33.55 MB per gx buffer
    _Float16* gx0 = (_Float16*)gxbase;
    int overlap = (ws_size >= (size_t)(512 << 10) + 256 + 2 * gxb) ? 1 : 0;
    _Float16* gx1 = overlap ? (_Float16*)(gxbase + gxb) : gx0;

    pack_w<<<1024, 256, 0, stream>>>(W_xh, wxp);
    hipMemsetAsync(bar, 0, 4, stream);
    lstm_coop<<<GRID, NTHR, 0, stream>>>(x, wxp, b_xh, b_hh, W_hh, out, gx0, gx1, bar, overlap);
}

// Round 19
// 2354.322 us; speedup vs baseline: 2.4740x; 1.1679x over previous
//
#include <hip/hip_runtime.h>
#include <hip/hip_fp16.h>

#define BB 64
#define TT 2048
#define DD 256
#define HH 256
#define CHUNK 256
#define NCHUNK 8
#define PB 2          // batches per serial block
#define ARS 272       // A row stride (bytes, i8)
#define NSER 32       // serial blocks
#define GRID 240      // total persistent blocks
#define NTHR 1024

typedef _Float16 f16x8 __attribute__((ext_vector_type(8)));
typedef _Float16 f16x4 __attribute__((ext_vector_type(4)));
typedef _Float16 h2t   __attribute__((ext_vector_type(2)));
typedef float    f32x4 __attribute__((ext_vector_type(4)));
typedef int      i32x4 __attribute__((ext_vector_type(4)));
union V8 { f16x8 v; h2t p[4]; };

__device__ __forceinline__ float sigm(float v){ return __builtin_amdgcn_rcpf(1.f+__expf(-v)); }
__device__ __forceinline__ float tanh_f(float v){ float e=__expf(2.f*v); return 1.f-2.f*__builtin_amdgcn_rcpf(e+1.f); }

// Pack W [256][1024] f32 (k-major) into f16 layout [k/8][1024][8]
__global__ void pack_w(const float* __restrict__ w, _Float16* __restrict__ o) {
    int idx = blockIdx.x * 256 + threadIdx.x;
    int j = idx & 1023;
    int k = idx >> 10;
    o[(((k >> 3) * 1024) + j) * 8 + (k & 7)] = (_Float16)w[idx];
}

// ---- grid barrier: flat monotonic counter, device scope, fenced ----
__device__ __forceinline__ void gridbar(int* bar, int gen) {
    __syncthreads();
    if (threadIdx.x == 0) {
        __builtin_amdgcn_fence(__ATOMIC_RELEASE, "agent");
        __hip_atomic_fetch_add(bar, 1, __ATOMIC_RELAXED, __HIP_MEMORY_SCOPE_AGENT);
        while (__hip_atomic_load(bar, __ATOMIC_RELAXED, __HIP_MEMORY_SCOPE_AGENT) < GRID * gen)
            __builtin_amdgcn_s_sleep(8);
        __builtin_amdgcn_fence(__ATOMIC_ACQUIRE, "agent");
    }
    __syncthreads();
}

union SMem {
    struct { char A[2 * 16 * ARS]; float cmax[1024]; } s;   // 8704 + 4096 B
    _Float16 xl[64 * 280];                                  // 35840 B
};

// gx = x @ W_xh + (b_xh + b_hh) for chunk c, grid-strided. 1024 threads.
// Layout: [t 256][sblk 32][b_local 2][dim 256][gate 4] f16.
__device__ void gemm_chunk(const float* __restrict__ x, const f16x8* __restrict__ wxp,
                           const float* __restrict__ b_xh, const float* __restrict__ b_hh,
                           _Float16* __restrict__ gxb, int c, _Float16* xl)
{
    const int tid = threadIdx.x;
    const int t0 = c << 8;
    const int tx = tid & 31;
    const int ty = tid >> 5;       // 0..31
    for (int T = (int)blockIdx.x - NSER; T < 2048; T += (GRID - NSER)) {
        const int rb = T >> 3, nb = T & 7;
        const int d = nb * 32 + tx;
        for (int it = 0; it < 4; ++it) {
            int idx = it * 1024 + tid, row = idx >> 6, kq = idx & 63;
            int rlin = rb * 64 + row, b = rlin >> 8, tl = rlin & 255;
            float4 v = *(const float4*)&x[((size_t)b * TT + t0 + tl) * DD + kq * 4];
            f16x4 h; h[0]=(_Float16)v.x; h[1]=(_Float16)v.y; h[2]=(_Float16)v.z; h[3]=(_Float16)v.w;
            *(f16x4*)&xl[row * 280 + kq * 4] = h;
        }
        __syncthreads();
        float acc[2][4] = {};
#pragma unroll 2
        for (int kk = 0; kk < 32; ++kk) {
            V8 wv[4], xv[2];
#pragma unroll
            for (int g = 0; g < 4; ++g) wv[g].v = wxp[kk * 1024 + g * 256 + d];
#pragma unroll
            for (int r = 0; r < 2; ++r) xv[r].v = *(const f16x8*)&xl[(ty + 32 * r) * 280 + kk * 8];
#pragma unroll
            for (int r = 0; r < 2; ++r)
#pragma unroll
                for (int g = 0; g < 4; ++g)
#pragma unroll
                    for (int q = 0; q < 4; ++q)
                        acc[r][g] = __builtin_amdgcn_fdot2(xv[r].p[q], wv[g].p[q], acc[r][g], false);
        }
        __syncthreads();
        float bb[4];
#pragma unroll
        for (int g = 0; g < 4; ++g) bb[g] = b_xh[g * 256 + d] + b_hh[g * 256 + d];
#pragma unroll
        for (int r = 0; r < 2; ++r) {
            int rlin = rb * 64 + ty + 32 * r, b = rlin >> 8, tl = rlin & 255;
            f16x4 o;
#pragma unroll
            for (int g = 0; g < 4; ++g) o[g] = (_Float16)(acc[r][g] + bb[g]);
            *(f16x4*)&gxb[((size_t)tl * 32 + (b >> 1)) * 2048 + (b & 1) * 1024 + d * 4] = o;
        }
    }
}

// ================= serial macros (i8 core, 16-dim waves, 1 cell/lane) =================
#define FOR_G(M) M(0) M(1) M(2) M(3)

#define DECLQ(g) i32x4 wq_##g##_0, wq_##g##_1, wq_##g##_2, wq_##g##_3; float sc_##g;

#define LOADQ1(g,kt,rs_) { \
    union { char c[16]; i32x4 v; } u_; \
    _Pragma("unroll") \
    for (int e = 0; e < 16; ++e) { \
        float w_ = W_hh[(size_t)((kt)*64 + l4*16 + e)*1024 + (g)*256 + wbase + l15]; \
        u_.c[e] = (char)(int)rintf(w_ * rs_); \
    } \
    wq_##g##_##kt = u_.v; }

#define LOADQ(g) { \
    float cm_ = cmax[(g)*256 + wbase + l15]; \
    float rs_ = 127.f / cm_; \
    sc_##g = cm_ * 6.2000124e-5f;   /* cm/(127*127) */ \
    LOADQ1(g,0,rs_) LOADQ1(g,1,rs_) LOADQ1(g,2,rs_) LOADQ1(g,3,rs_) }

// per kt: one b128 A-frag read shared by the 4 gate MFMAs
#define QKT(kt) { \
    i32x4 af_ = *(const i32x4*)&Apar[(kt)*64 + l4*16]; \
    ia0_ = __builtin_amdgcn_mfma_i32_16x16x64_i8(af_, wq_0_##kt, ia0_, 0,0,0); \
    ia1_ = __builtin_amdgcn_mfma_i32_16x16x64_i8(af_, wq_1_##kt, ia1_, 0,0,0); \
    ia2_ = __builtin_amdgcn_mfma_i32_16x16x64_i8(af_, wq_2_##kt, ia2_, 0,0,0); \
    ia3_ = __builtin_amdgcn_mfma_i32_16x16x64_i8(af_, wq_3_##kt, ia3_, 0,0,0); }

// Persistent fused kernel: blocks 0..31 = serial recurrence (1024 thr, 16 waves,
// 4 waves/SIMD, ONE cell per lane), rest = gx GEMM.
// Lane role: b_ = l4>>1 (local batch), ly = l4&1 (layer).
// A rows: h0(b) at rows 8b and 8b+4 (dup); h1(b) at row 8b+5; others zero.
// MFMA C-layout row = 4*l4 + reg: layer0 lane reads reg0 = d0;
// layer1 lane reads reg0 = d0 (dup row), reg1 = d1 — shared-d0 stays in-lane.
__global__ __launch_bounds__(NTHR, 1) void lstm_coop(
    const float* __restrict__ x,
    const _Float16* __restrict__ wxp16,
    const float* __restrict__ b_xh, const float* __restrict__ b_hh,
    const float* __restrict__ W_hh,
    float* __restrict__ out,
    _Float16* __restrict__ gx0, _Float16* __restrict__ gx1,
    int* __restrict__ bar, int overlap)
{
    __shared__ SMem sm;
    const int tid = threadIdx.x;
    const f16x8* wxp = (const f16x8*)wxp16;

    if (blockIdx.x < NSER) {
        // ================= serial path =================
        char*  A    = sm.s.A;
        float* cmax = sm.s.cmax;
        const int blk = blockIdx.x;
        const int l   = tid & 63;
        const int l15 = l & 15;
        const int l4  = l >> 4;
        const int w   = tid >> 6;          // 0..15
        const int wbase = w * 16;          // this wave's 16 dims
        const int b_  = l4 >> 1;           // local batch 0..1
        const int ly  = l4 & 1;            // 0 = layer0, 1 = layer1
        const int gb  = blk * PB + b_;     // global batch
        const int d_  = wbase + l15;       // this lane's dim

        // per-column absmax of W_hh (cooperative)
        for (int col = tid; col < 1024; col += NTHR) {
            float m = 1e-20f;
            for (int k = 0; k < 256; ++k)
                m = fmaxf(m, fabsf(W_hh[(size_t)k * 1024 + col]));
            cmax[col] = m;
        }
        __syncthreads();

        // quantized weight registers: 16 named i32x4 (=64 regs) + 4 scales
        FOR_G(DECLQ)
        FOR_G(LOADQ)

        float bh2_0 = 2.f*b_hh[0*256 + d_], bh2_1 = 2.f*b_hh[1*256 + d_];
        float bh2_2 = 2.f*b_hh[2*256 + d_], bh2_3 = 2.f*b_hh[3*256 + d_];

        float cs = 0.f;
        for (int i = tid; i < 2 * 16 * ARS; i += NTHR) A[i] = 0;   // h(0) = 0

        int gen = 0;
        gridbar(bar, ++gen);                 // wait for chunk-0 gx

        const size_t FIN = (size_t)BB * TT * HH;
        for (int c = 0; c < NCHUNK; ++c) {
            const _Float16* gxc = (c & 1) ? gx1 : gx0;
            const int t0 = c << 8;
            const int nph = (c == NCHUNK - 1) ? CHUNK + 1 : CHUNK;
            const bool lastc = (c == NCHUNK - 1);
            const _Float16* gxp = gxc + (size_t)blk * 2048 + b_ * 1024 + d_ * 4;
            for (int p = 0; p < nph; ++p) {
                const int par = p & 1, parx = par ^ 1;
                const bool l0act = (p < CHUNK);
                const bool l1act = (c > 0) || (p > 0);
                const char* Apar = A + par * (16 * ARS) + l15 * ARS;

                f16x4 gv_ = {};
                if (l0act && !ly) gv_ = *(const f16x4*)gxp;

                i32x4 ia0_ = {}, ia1_ = {}, ia2_ = {}, ia3_ = {};
                QKT(0) QKT(1) QKT(2) QKT(3)

                // ---- update: one cell per lane ----
                float gi_, gf_, gg_, go_;
                if (ly) {
                    gi_ = (float)(ia0_[0] + ia0_[1]) * sc_0 + bh2_0;
                    gf_ = (float)(ia1_[0] + ia1_[1]) * sc_1 + bh2_1;
                    gg_ = (float)(ia2_[0] + ia2_[1]) * sc_2 + bh2_2;
                    go_ = (float)(ia3_[0] + ia3_[1]) * sc_3 + bh2_3;
                } else {
                    gi_ = (float)ia0_[0] * sc_0 + (float)gv_[0];
                    gf_ = (float)ia1_[0] * sc_1 + (float)gv_[1];
                    gg_ = (float)ia2_[0] * sc_2 + (float)gv_[2];
                    go_ = (float)ia3_[0] * sc_3 + (float)gv_[3];
                }
                const bool act = ly ? l1act : l0act;
                float hn_ = 0.f;
                if (act) {
                    cs = cs * sigm(gf_) + sigm(gi_) * tanh_f(gg_);
                    hn_ = sigm(go_) * tanh_f(cs);
                }
                const char q_ = (char)(int)rintf(hn_ * 127.f);
                if (!ly) {
                    A[(parx*16 + 8*b_ + 0)*ARS + d_] = q_;
                    A[(parx*16 + 8*b_ + 4)*ARS + d_] = q_;   // dup for layer1's d0
                } else {
                    A[(parx*16 + 8*b_ + 5)*ARS + d_] = q_;
                    if (act) out[((size_t)gb*TT + (t0 + p - 1))*HH + d_] = hn_;
                }
                if (lastc) {
                    if (!ly && l0act && p == CHUNK-1) {
                        out[FIN +         gb*256 + d_] = hn_;
                        out[FIN + 32768 + gb*256 + d_] = cs;
                    }
                    if (ly && p == nph-1) {
                        out[FIN + 16384 + gb*256 + d_] = hn_;
                        out[FIN + 49152 + gb*256 + d_] = cs;
                    }
                }

                gxp += 65536;
                if (p + 1 < nph) {
                    // only LDS (A) writes need cross-wave visibility
                    asm volatile("s_waitcnt lgkmcnt(0)" ::: "memory");
                    __builtin_amdgcn_s_barrier();
                }
            }
            if (c < NCHUNK - 1) {
                gridbar(bar, ++gen);
                if (!overlap) gridbar(bar, ++gen);
            }
        }
    } else {
        // ================= gemm path =================
        gemm_chunk(x, wxp, b_xh, b_hh, gx0, 0, sm.xl);
        int gen = 0;
        gridbar(bar, ++gen);
        for (int c = 0; c < NCHUNK - 1; ++c) {
            if (overlap) {
                gemm_chunk(x, wxp, b_xh, b_hh, ((c + 1) & 1) ? gx1 : gx0, c + 1, sm.xl);
                gridbar(bar, ++gen);
            } else {
                gridbar(bar, ++gen);
                gemm_chunk(x, wxp, b_xh, b_hh, gx0, c + 1, sm.xl);
                gridbar(bar, ++gen);
            }
        }
    }
}

extern "C" void kernel_launch(void* const* d_in, const int* in_sizes, int n_in,
                              void* d_out, int out_size, void* d_ws, size_t ws_size,
                              hipStream_t stream) {
    const float* x    = (const float*)d_in[0];
    const float* W_xh = (const float*)d_in[1];
    const float* b_xh = (const float*)d_in[2];
    const float* W_hh = (const float*)d_in[3];
    const float* b_hh = (const float*)d_in[4];
    float* out = (float*)d_out;

    char* ws = (char*)d_ws;
    _Float16* wxp = (_Float16*)ws;                          // 512 KB packed W_xh
    int* bar      = (int*)(ws + (512 << 10));               // barrier counter
    char* gxbase  = ws + (512 << 10) + 256;
    const size_t gxb = (size_t)64 * 256 * 1024 * 2;         // 33.55 MB per gx buffer
    _Float16* gx0 = (_Float16*)gxbase;
    int overlap = (ws_size >= (size_t)(512 << 10) + 256 + 2 * gxb) ? 1 : 0;
    _Float16* gx1 = overlap ? (_Float16*)(gxbase + gxb) : gx0;

    pack_w<<<1024, 256, 0, stream>>>(W_xh, wxp);
    hipMemsetAsync(bar, 0, 4, stream);
    lstm_coop<<<GRID, NTHR, 0, stream>>>(x, wxp, b_xh, b_hh, W_hh, out, gx0, gx1, bar, overlap);
}

// Round 20
// 2352.747 us; speedup vs baseline: 2.4757x; 1.0007x over previous
//
#include <hip/hip_runtime.h>
#include <hip/hip_fp16.h>

#define BB 64
#define TT 2048
#define DD 256
#define HH 256
#define CHUNK 256
#define NCHUNK 8
#define PB 2          // batches per serial block
#define ARS 272       // A row stride (bytes, i8)
#define NSER 32       // serial blocks
#define GRID 240      // total persistent blocks
#define NTHR 1024

typedef _Float16 f16x8 __attribute__((ext_vector_type(8)));
typedef _Float16 f16x4 __attribute__((ext_vector_type(4)));
typedef _Float16 h2t   __attribute__((ext_vector_type(2)));
typedef float    f32x4 __attribute__((ext_vector_type(4)));
typedef int      i32x4 __attribute__((ext_vector_type(4)));
union V8 { f16x8 v; h2t p[4]; };

__device__ __forceinline__ float sigm(float v){ return __builtin_amdgcn_rcpf(1.f+__expf(-v)); }
__device__ __forceinline__ float tanh_f(float v){ float e=__expf(2.f*v); return 1.f-2.f*__builtin_amdgcn_rcpf(e+1.f); }

// Pack W [256][1024] f32 (k-major) into f16 layout [k/8][1024][8]
__global__ void pack_w(const float* __restrict__ w, _Float16* __restrict__ o) {
    int idx = blockIdx.x * 256 + threadIdx.x;
    int j = idx & 1023;
    int k = idx >> 10;
    o[(((k >> 3) * 1024) + j) * 8 + (k & 7)] = (_Float16)w[idx];
}

// ---- grid barrier: flat monotonic counter, device scope, fenced ----
__device__ __forceinline__ void gridbar(int* bar, int gen) {
    __syncthreads();
    if (threadIdx.x == 0) {
        __builtin_amdgcn_fence(__ATOMIC_RELEASE, "agent");
        __hip_atomic_fetch_add(bar, 1, __ATOMIC_RELAXED, __HIP_MEMORY_SCOPE_AGENT);
        while (__hip_atomic_load(bar, __ATOMIC_RELAXED, __HIP_MEMORY_SCOPE_AGENT) < GRID * gen)
            __builtin_amdgcn_s_sleep(8);
        __builtin_amdgcn_fence(__ATOMIC_ACQUIRE, "agent");
    }
    __syncthreads();
}

union SMem {
    struct { char A[2 * 16 * ARS]; float cmax[1024]; } s;   // 8704 + 4096 B
    _Float16 xl[64 * 280];                                  // 35840 B
};

// gx = x @ W_xh + (b_xh + b_hh) for chunk c, grid-strided. 1024 threads.
// Layout: [t 256][sblk 32][b_local 2][dim 256][gate 4] f16.
__device__ void gemm_chunk(const float* __restrict__ x, const f16x8* __restrict__ wxp,
                           const float* __restrict__ b_xh, const float* __restrict__ b_hh,
                           _Float16* __restrict__ gxb, int c, _Float16* xl)
{
    const int tid = threadIdx.x;
    const int t0 = c << 8;
    const int tx = tid & 31;
    const int ty = tid >> 5;       // 0..31
    for (int T = (int)blockIdx.x - NSER; T < 2048; T += (GRID - NSER)) {
        const int rb = T >> 3, nb = T & 7;
        const int d = nb * 32 + tx;
        for (int it = 0; it < 4; ++it) {
            int idx = it * 1024 + tid, row = idx >> 6, kq = idx & 63;
            int rlin = rb * 64 + row, b = rlin >> 8, tl = rlin & 255;
            float4 v = *(const float4*)&x[((size_t)b * TT + t0 + tl) * DD + kq * 4];
            f16x4 h; h[0]=(_Float16)v.x; h[1]=(_Float16)v.y; h[2]=(_Float16)v.z; h[3]=(_Float16)v.w;
            *(f16x4*)&xl[row * 280 + kq * 4] = h;
        }
        __syncthreads();
        float acc[2][4] = {};
#pragma unroll 2
        for (int kk = 0; kk < 32; ++kk) {
            V8 wv[4], xv[2];
#pragma unroll
            for (int g = 0; g < 4; ++g) wv[g].v = wxp[kk * 1024 + g * 256 + d];
#pragma unroll
            for (int r = 0; r < 2; ++r) xv[r].v = *(const f16x8*)&xl[(ty + 32 * r) * 280 + kk * 8];
#pragma unroll
            for (int r = 0; r < 2; ++r)
#pragma unroll
                for (int g = 0; g < 4; ++g)
#pragma unroll
                    for (int q = 0; q < 4; ++q)
                        acc[r][g] = __builtin_amdgcn_fdot2(xv[r].p[q], wv[g].p[q], acc[r][g], false);
        }
        __syncthreads();
        float bb[4];
#pragma unroll
        for (int g = 0; g < 4; ++g) bb[g] = b_xh[g * 256 + d] + b_hh[g * 256 + d];
#pragma unroll
        for (int r = 0; r < 2; ++r) {
            int rlin = rb * 64 + ty + 32 * r, b = rlin >> 8, tl = rlin & 255;
            f16x4 o;
#pragma unroll
            for (int g = 0; g < 4; ++g) o[g] = (_Float16)(acc[r][g] + bb[g]);
            *(f16x4*)&gxb[((size_t)tl * 32 + (b >> 1)) * 2048 + (b & 1) * 1024 + d * 4] = o;
        }
    }
}

// ================= serial macros (i8 core, 16-dim waves, 1 cell/lane) =================
#define FOR_G(M) M(0) M(1) M(2) M(3)

#define DECLQ(g) i32x4 wq_##g##_0, wq_##g##_1, wq_##g##_2, wq_##g##_3; float sc_##g;

#define LOADQ1(g,kt,rs_) { \
    union { char c[16]; i32x4 v; } u_; \
    _Pragma("unroll") \
    for (int e = 0; e < 16; ++e) { \
        float w_ = W_hh[(size_t)((kt)*64 + l4*16 + e)*1024 + (g)*256 + wbase + l15]; \
        u_.c[e] = (char)(int)rintf(w_ * rs_); \
    } \
    wq_##g##_##kt = u_.v; }

#define LOADQ(g) { \
    float cm_ = cmax[(g)*256 + wbase + l15]; \
    float rs_ = 127.f / cm_; \
    sc_##g = cm_ * 6.2000124e-5f;   /* cm/(127*127) */ \
    LOADQ1(g,0,rs_) LOADQ1(g,1,rs_) LOADQ1(g,2,rs_) LOADQ1(g,3,rs_) }

// per kt: one b128 A-frag read shared by the 4 gate MFMAs
#define QKT(kt) { \
    i32x4 af_ = *(const i32x4*)&Apar[(kt)*64 + l4*16]; \
    ia0_ = __builtin_amdgcn_mfma_i32_16x16x64_i8(af_, wq_0_##kt, ia0_, 0,0,0); \
    ia1_ = __builtin_amdgcn_mfma_i32_16x16x64_i8(af_, wq_1_##kt, ia1_, 0,0,0); \
    ia2_ = __builtin_amdgcn_mfma_i32_16x16x64_i8(af_, wq_2_##kt, ia2_, 0,0,0); \
    ia3_ = __builtin_amdgcn_mfma_i32_16x16x64_i8(af_, wq_3_##kt, ia3_, 0,0,0); }

// Persistent fused kernel: blocks 0..31 = serial recurrence (1024 thr, 16 waves,
// 4 waves/SIMD, ONE cell per lane), rest = gx GEMM.
// Lane role: b_ = l4>>1 (local batch), ly = l4&1 (layer).
// A rows: h0(b) at rows 8b and 8b+4 (dup); h1(b) at row 8b+5; others zero.
// gx loads are software-pipelined ONE PHASE ahead (gvn -> gv_), hiding the
// ~900cy HBM latency under a full phase (r20: register file has slack now).
__global__ __launch_bounds__(NTHR, 1) void lstm_coop(
    const float* __restrict__ x,
    const _Float16* __restrict__ wxp16,
    const float* __restrict__ b_xh, const float* __restrict__ b_hh,
    const float* __restrict__ W_hh,
    float* __restrict__ out,
    _Float16* __restrict__ gx0, _Float16* __restrict__ gx1,
    int* __restrict__ bar, int overlap)
{
    __shared__ SMem sm;
    const int tid = threadIdx.x;
    const f16x8* wxp = (const f16x8*)wxp16;

    if (blockIdx.x < NSER) {
        // ================= serial path =================
        char*  A    = sm.s.A;
        float* cmax = sm.s.cmax;
        const int blk = blockIdx.x;
        const int l   = tid & 63;
        const int l15 = l & 15;
        const int l4  = l >> 4;
        const int w   = tid >> 6;          // 0..15
        const int wbase = w * 16;          // this wave's 16 dims
        const int b_  = l4 >> 1;           // local batch 0..1
        const int ly  = l4 & 1;            // 0 = layer0, 1 = layer1
        const int gb  = blk * PB + b_;     // global batch
        const int d_  = wbase + l15;       // this lane's dim

        // per-column absmax of W_hh (cooperative)
        for (int col = tid; col < 1024; col += NTHR) {
            float m = 1e-20f;
            for (int k = 0; k < 256; ++k)
                m = fmaxf(m, fabsf(W_hh[(size_t)k * 1024 + col]));
            cmax[col] = m;
        }
        __syncthreads();

        // quantized weight registers: 16 named i32x4 (=64 regs) + 4 scales
        FOR_G(DECLQ)
        FOR_G(LOADQ)

        float bh2_0 = 2.f*b_hh[0*256 + d_], bh2_1 = 2.f*b_hh[1*256 + d_];
        float bh2_2 = 2.f*b_hh[2*256 + d_], bh2_3 = 2.f*b_hh[3*256 + d_];

        float cs = 0.f;
        for (int i = tid; i < 2 * 16 * ARS; i += NTHR) A[i] = 0;   // h(0) = 0

        int gen = 0;
        gridbar(bar, ++gen);                 // wait for chunk-0 gx

        const size_t FIN = (size_t)BB * TT * HH;
        for (int c = 0; c < NCHUNK; ++c) {
            const _Float16* gxc = (c & 1) ? gx1 : gx0;
            const int t0 = c << 8;
            const int nph = (c == NCHUNK - 1) ? CHUNK + 1 : CHUNK;
            const bool lastc = (c == NCHUNK - 1);
            const _Float16* gxp = gxc + (size_t)blk * 2048 + b_ * 1024 + d_ * 4;

            // chunk prologue: prefetch phase-0 gv
            f16x4 gvn = {};
            if (!ly) gvn = *(const f16x4*)gxp;
            gxp += 65536;

            for (int p = 0; p < nph; ++p) {
                const int par = p & 1, parx = par ^ 1;
                const bool l0act = (p < CHUNK);
                const bool l1act = (c > 0) || (p > 0);
                const char* Apar = A + par * (16 * ARS) + l15 * ARS;

                // rotate prefetch -> current; issue NEXT phase's load now
                // (consumed ~1 full phase later: HBM latency fully hidden)
                f16x4 gv_ = gvn;
                if (p + 1 < CHUNK) {
                    if (!ly) gvn = *(const f16x4*)gxp;
                } else {
                    gvn = (f16x4){};
                }
                gxp += 65536;

                i32x4 ia0_ = {}, ia1_ = {}, ia2_ = {}, ia3_ = {};
                QKT(0) QKT(1) QKT(2) QKT(3)

                // ---- update: one cell per lane ----
                float gi_, gf_, gg_, go_;
                if (ly) {
                    gi_ = (float)(ia0_[0] + ia0_[1]) * sc_0 + bh2_0;
                    gf_ = (float)(ia1_[0] + ia1_[1]) * sc_1 + bh2_1;
                    gg_ = (float)(ia2_[0] + ia2_[1]) * sc_2 + bh2_2;
                    go_ = (float)(ia3_[0] + ia3_[1]) * sc_3 + bh2_3;
                } else {
                    gi_ = (float)ia0_[0] * sc_0 + (float)gv_[0];
                    gf_ = (float)ia1_[0] * sc_1 + (float)gv_[1];
                    gg_ = (float)ia2_[0] * sc_2 + (float)gv_[2];
                    go_ = (float)ia3_[0] * sc_3 + (float)gv_[3];
                }
                const bool act = ly ? l1act : l0act;
                float hn_ = 0.f;
                if (act) {
                    cs = cs * sigm(gf_) + sigm(gi_) * tanh_f(gg_);
                    hn_ = sigm(go_) * tanh_f(cs);
                }
                const char q_ = (char)(int)rintf(hn_ * 127.f);
                if (!ly) {
                    A[(parx*16 + 8*b_ + 0)*ARS + d_] = q_;
                    A[(parx*16 + 8*b_ + 4)*ARS + d_] = q_;   // dup for layer1's d0
                } else {
                    A[(parx*16 + 8*b_ + 5)*ARS + d_] = q_;
                    if (act) out[((size_t)gb*TT + (t0 + p - 1))*HH + d_] = hn_;
                }
                if (lastc) {
                    if (!ly && l0act && p == CHUNK-1) {
                        out[FIN +         gb*256 + d_] = hn_;
                        out[FIN + 32768 + gb*256 + d_] = cs;
                    }
                    if (ly && p == nph-1) {
                        out[FIN + 16384 + gb*256 + d_] = hn_;
                        out[FIN + 49152 + gb*256 + d_] = cs;
                    }
                }

                if (p + 1 < nph) {
                    // only LDS (A) writes need cross-wave visibility
                    asm volatile("s_waitcnt lgkmcnt(0)" ::: "memory");
                    __builtin_amdgcn_s_barrier();
                }
            }
            if (c < NCHUNK - 1) {
                gridbar(bar, ++gen);
                if (!overlap) gridbar(bar, ++gen);
            }
        }
    } else {
        // ================= gemm path =================
        gemm_chunk(x, wxp, b_xh, b_hh, gx0, 0, sm.xl);
        int gen = 0;
        gridbar(bar, ++gen);
        for (int c = 0; c < NCHUNK - 1; ++c) {
            if (overlap) {
                gemm_chunk(x, wxp, b_xh, b_hh, ((c + 1) & 1) ? gx1 : gx0, c + 1, sm.xl);
                gridbar(bar, ++gen);
            } else {
                gridbar(bar, ++gen);
                gemm_chunk(x, wxp, b_xh, b_hh, gx0, c + 1, sm.xl);
                gridbar(bar, ++gen);
            }
        }
    }
}

extern "C" void kernel_launch(void* const* d_in, const int* in_sizes, int n_in,
                              void* d_out, int out_size, void* d_ws, size_t ws_size,
                              hipStream_t stream) {
    const float* x    = (const float*)d_in[0];
    const float* W_xh = (const float*)d_in[1];
    const float* b_xh = (const float*)d_in[2];
    const float* W_hh = (const float*)d_in[3];
    const float* b_hh = (const float*)d_in[4];
    float* out = (float*)d_out;

    char* ws = (char*)d_ws;
    _Float16* wxp = (_Float16*)ws;                          // 512 KB packed W_xh
    int* bar      = (int*)(ws + (512 << 10));               // barrier counter
    char* gxbase  = ws + (512 << 10) + 256;
    const size_t gxb = (size_t)64 * 256 * 1024 * 2;         // 33.55 MB per gx buffer
    _Float16* gx0 = (_Float16*)gxbase;
    int overlap = (ws_size >= (size_t)(512 << 10) + 256 + 2 * gxb) ? 1 : 0;
    _Float16* gx1 = overlap ? (_Float16*)(gxbase + gxb) : gx0;

    pack_w<<<1024, 256, 0, stream>>>(W_xh, wxp);
    hipMemsetAsync(bar, 0, 4, stream);
    lstm_coop<<<GRID, NTHR, 0, stream>>>(x, wxp, b_xh, b_hh, W_hh, out, gx0, gx1, bar, overlap);
}